// Round 5
// baseline (176.261 us; speedup 1.0000x reference)
//
#include <hip/hip_runtime.h>

#define S1_BLOCKS 2048
#define S1_THREADS 256

// Fused single-pass MPJPE: grid-stride over 4-triplet groups with direct
// strided dwordx4 loads (proven equal-fastest structure, lowest VGPR),
// per-block partial -> ws, last-finished block reduces partials and writes
// the mean. Counter (4 B at ws[S1_BLOCKS]) is zeroed by hipMemsetAsync at
// the top of every kernel_launch call (stream-ordered, graph-capturable).
__global__ __launch_bounds__(S1_THREADS) void mpjpe_fused(
    const float4* __restrict__ pred4,
    const float4* __restrict__ gt4,
    float* __restrict__ partials,
    unsigned int* __restrict__ counter,
    float* __restrict__ out,
    long long n_groups,     // n_samples * 16
    double inv_count)       // 1 / (n_samples * 63)
{
    long long tid = (long long)blockIdx.x * blockDim.x + threadIdx.x;
    long long stride = (long long)gridDim.x * blockDim.x;

    float acc = 0.0f;
    #pragma unroll 2
    for (long long g = tid; g < n_groups; g += stride) {
        long long base = g * 3;               // 3 float4 per 4 triplets
        float4 p0 = pred4[base];
        float4 p1 = pred4[base + 1];
        float4 p2 = pred4[base + 2];
        float4 q0 = gt4[base];
        float4 q1 = gt4[base + 1];
        float4 q2 = gt4[base + 2];

        // triplet 0: joint (4g)&63 == 0 iff (g&15)==0 -> masked out
        float dx = p0.x - q0.x, dy = p0.y - q0.y, dz = p0.z - q0.z;
        float num = dx*dx + dy*dy + dz*dz;
        float den = q0.x*q0.x + q0.y*q0.y + q0.z*q0.z;
        float r0 = sqrtf(num / den);
        acc += ((g & 15) == 0) ? 0.0f : r0;

        // triplet 1: (p0.w, p1.x, p1.y)
        dx = p0.w - q0.w; dy = p1.x - q1.x; dz = p1.y - q1.y;
        num = dx*dx + dy*dy + dz*dz;
        den = q0.w*q0.w + q1.x*q1.x + q1.y*q1.y;
        acc += sqrtf(num / den);

        // triplet 2: (p1.z, p1.w, p2.x)
        dx = p1.z - q1.z; dy = p1.w - q1.w; dz = p2.x - q2.x;
        num = dx*dx + dy*dy + dz*dz;
        den = q1.z*q1.z + q1.w*q1.w + q2.x*q2.x;
        acc += sqrtf(num / den);

        // triplet 3: (p2.y, p2.z, p2.w)
        dx = p2.y - q2.y; dy = p2.z - q2.z; dz = p2.w - q2.w;
        num = dx*dx + dy*dy + dz*dz;
        den = q2.y*q2.y + q2.z*q2.z + q2.w*q2.w;
        acc += sqrtf(num / den);
    }

    // wave-64 reduce
    #pragma unroll
    for (int off = 32; off > 0; off >>= 1)
        acc += __shfl_down(acc, off, 64);

    __shared__ float wsum[S1_THREADS / 64];
    int lane = threadIdx.x & 63;
    int wv   = threadIdx.x >> 6;
    if (lane == 0) wsum[wv] = acc;
    __syncthreads();

    __shared__ bool last;
    if (threadIdx.x == 0) {
        float s = wsum[0] + wsum[1] + wsum[2] + wsum[3];
        partials[blockIdx.x] = s;
        __threadfence();                       // release partial (device scope)
        unsigned int old = atomicAdd(counter, 1u);
        last = (old == gridDim.x - 1);
    }
    __syncthreads();

    if (last) {
        __threadfence();                       // acquire all partials
        double dacc = 0.0;
        for (int i = threadIdx.x; i < gridDim.x; i += blockDim.x)
            dacc += (double)partials[i];

        #pragma unroll
        for (int off = 32; off > 0; off >>= 1)
            dacc += __shfl_down(dacc, off, 64);

        __shared__ double dsum[S1_THREADS / 64];
        if (lane == 0) dsum[wv] = dacc;
        __syncthreads();

        if (threadIdx.x == 0) {
            double s = dsum[0] + dsum[1] + dsum[2] + dsum[3];
            out[0] = (float)(s * inv_count);
        }
    }
}

extern "C" void kernel_launch(void* const* d_in, const int* in_sizes, int n_in,
                              void* d_out, int out_size, void* d_ws, size_t ws_size,
                              hipStream_t stream) {
    const float4* pred = (const float4*)d_in[0];
    const float4* gt   = (const float4*)d_in[1];
    float* out = (float*)d_out;
    float* partials = (float*)d_ws;
    unsigned int* counter = (unsigned int*)((char*)d_ws + S1_BLOCKS * sizeof(float));

    long long n_samples = (long long)in_sizes[0] / 192;   // P=64, D=3
    long long n_groups  = n_samples * 16;                 // 64 joints / 4
    long long n_joints  = n_samples * 63;

    hipMemsetAsync(counter, 0, sizeof(unsigned int), stream);
    mpjpe_fused<<<S1_BLOCKS, S1_THREADS, 0, stream>>>(
        pred, gt, partials, counter, out, n_groups, 1.0 / (double)n_joints);
}

// Round 6
// 74.001 us; speedup vs baseline: 2.3819x; 2.3819x over previous
//
#include <hip/hip_runtime.h>

#define S1_BLOCKS 2048
#define S1_THREADS 256

// Stage 1: each iteration a thread handles 4 consecutive (sample,joint)
// triplets = 48 B from pred and 48 B from gt via 3x dwordx4 each.
// Joint 0 of each sample is loaded (shares cache lines) but masked out.
// NOTE: fused single-kernel variant with per-block __threadfence() was 2.4x
// SLOWER (R5): device-scope fences emit per-block L2 writeback/invalidate on
// non-coherent multi-XCD L2s. Two kernels + implicit boundary is cheaper.
__global__ __launch_bounds__(S1_THREADS) void mpjpe_stage1(
    const float4* __restrict__ pred4,
    const float4* __restrict__ gt4,
    float* __restrict__ partials,
    long long n_groups)   // n_samples * 64 / 4
{
    long long tid = (long long)blockIdx.x * blockDim.x + threadIdx.x;
    long long stride = (long long)gridDim.x * blockDim.x;

    float acc = 0.0f;
    #pragma unroll 2
    for (long long g = tid; g < n_groups; g += stride) {
        long long base = g * 3;               // 3 float4 per 4 triplets
        float4 p0 = pred4[base];
        float4 p1 = pred4[base + 1];
        float4 p2 = pred4[base + 2];
        float4 q0 = gt4[base];
        float4 q1 = gt4[base + 1];
        float4 q2 = gt4[base + 2];

        // triplet 0: p0.xyz ; joint (4g)&63 == 0 iff (g&15)==0 -> masked
        float dx = p0.x - q0.x, dy = p0.y - q0.y, dz = p0.z - q0.z;
        float num = dx*dx + dy*dy + dz*dz;
        float den = q0.x*q0.x + q0.y*q0.y + q0.z*q0.z;
        float r0 = sqrtf(num / den);
        acc += ((g & 15) == 0) ? 0.0f : r0;

        // triplet 1: (p0.w, p1.x, p1.y)
        dx = p0.w - q0.w; dy = p1.x - q1.x; dz = p1.y - q1.y;
        num = dx*dx + dy*dy + dz*dz;
        den = q0.w*q0.w + q1.x*q1.x + q1.y*q1.y;
        acc += sqrtf(num / den);

        // triplet 2: (p1.z, p1.w, p2.x)
        dx = p1.z - q1.z; dy = p1.w - q1.w; dz = p2.x - q2.x;
        num = dx*dx + dy*dy + dz*dz;
        den = q1.z*q1.z + q1.w*q1.w + q2.x*q2.x;
        acc += sqrtf(num / den);

        // triplet 3: (p2.y, p2.z, p2.w)
        dx = p2.y - q2.y; dy = p2.z - q2.z; dz = p2.w - q2.w;
        num = dx*dx + dy*dy + dz*dz;
        den = q2.y*q2.y + q2.z*q2.z + q2.w*q2.w;
        acc += sqrtf(num / den);
    }

    // wave-64 reduce
    #pragma unroll
    for (int off = 32; off > 0; off >>= 1)
        acc += __shfl_down(acc, off, 64);

    __shared__ float wsum[S1_THREADS / 64];
    int lane = threadIdx.x & 63;
    int wave = threadIdx.x >> 6;
    if (lane == 0) wsum[wave] = acc;
    __syncthreads();

    if (threadIdx.x == 0) {
        float s = 0.0f;
        #pragma unroll
        for (int w = 0; w < S1_THREADS / 64; ++w) s += wsum[w];
        partials[blockIdx.x] = s;
    }
}

// Stage 2: reduce S1_BLOCKS partials (double accum) -> mean scalar.
__global__ __launch_bounds__(256) void mpjpe_stage2(
    const float* __restrict__ partials,
    float* __restrict__ out,
    int n, double inv_count)
{
    double acc = 0.0;
    for (int i = threadIdx.x; i < n; i += blockDim.x)
        acc += (double)partials[i];

    #pragma unroll
    for (int off = 32; off > 0; off >>= 1)
        acc += __shfl_down(acc, off, 64);

    __shared__ double wsum[256 / 64];
    int lane = threadIdx.x & 63;
    int wave = threadIdx.x >> 6;
    if (lane == 0) wsum[wave] = acc;
    __syncthreads();

    if (threadIdx.x == 0) {
        double s = 0.0;
        #pragma unroll
        for (int w = 0; w < 256 / 64; ++w) s += wsum[w];
        out[0] = (float)(s * inv_count);
    }
}

extern "C" void kernel_launch(void* const* d_in, const int* in_sizes, int n_in,
                              void* d_out, int out_size, void* d_ws, size_t ws_size,
                              hipStream_t stream) {
    const float4* pred = (const float4*)d_in[0];
    const float4* gt   = (const float4*)d_in[1];
    float* out = (float*)d_out;
    float* partials = (float*)d_ws;

    long long n_samples = (long long)in_sizes[0] / 192;   // P=64, D=3
    long long n_groups  = n_samples * 16;                 // 64 joints / 4
    long long n_joints  = n_samples * 63;

    mpjpe_stage1<<<S1_BLOCKS, S1_THREADS, 0, stream>>>(pred, gt, partials, n_groups);
    mpjpe_stage2<<<1, 256, 0, stream>>>(partials, out, S1_BLOCKS,
                                        1.0 / (double)n_joints);
}